// Round 9
// baseline (258.634 us; speedup 1.0000x reference)
//
#include <hip/hip_runtime.h>
#include <hip/hip_fp16.h>

#define NF 128   // feature dim, fixed by the problem

typedef _Float16 half8 __attribute__((ext_vector_type(8)));
typedef float    floatx4 __attribute__((ext_vector_type(4)));

// ---------------- prep: zero cnt + convert/transpose W1,W2 to fp16 ----------------
__global__ __launch_bounds__(256) void prep_k(
    int* __restrict__ cnt, int n, int nb,
    const float* __restrict__ W1, const float* __restrict__ W2,
    __half* __restrict__ WT1, __half* __restrict__ WT2)
{
    int b = blockIdx.x;
    if (b < nb) {
        int i = b * 256 + threadIdx.x;
        if (i < n) cnt[i] = 0;
    } else {
        int idx = (b - nb) * 256 + threadIdx.x;   // 0..32767
        const float* W = (idx < 16384) ? W1 : W2;
        __half* WT     = (idx < 16384) ? WT1 : WT2;
        int j = idx & 16383;
        int nn = j & 127, k = j >> 7;
        WT[nn * NF + k] = __float2half(W[k * NF + nn]);   // WT[n][k] = W[k][n]
    }
}

// ---------------- count: 4 edges/thread (dst guaranteed in [0,N)) ----------------
__global__ __launch_bounds__(256) void count_k(const int* __restrict__ dst,
                                               int* __restrict__ cnt, int E) {
    int e = (blockIdx.x * 256 + threadIdx.x) * 4;
    if (e + 3 < E) {
        int4 d = *(const int4*)(dst + e);
        atomicAdd(&cnt[d.x], 1); atomicAdd(&cnt[d.y], 1);
        atomicAdd(&cnt[d.z], 1); atomicAdd(&cnt[d.w], 1);
    } else {
        for (int k = e; k < E; k++) atomicAdd(&cnt[dst[k]], 1);
    }
}

// Phase 1: per-256-chunk local exclusive scan (into rowptr) + block totals + dinv.
__global__ __launch_bounds__(256) void pscan_local(
    const int* __restrict__ cnt, float* __restrict__ dinv,
    int* __restrict__ rowptr, int* __restrict__ blocksum, int n)
{
    __shared__ int sm[256];
    int tid = threadIdx.x;
    int i = blockIdx.x * 256 + tid;
    int v = (i < n) ? cnt[i] : 0;
    if (i < n) dinv[i] = rsqrtf((float)v + 1.0f);  // +1 = self-loop
    sm[tid] = v;
    __syncthreads();
    #pragma unroll
    for (int d = 1; d < 256; d <<= 1) {
        int t = (tid >= d) ? sm[tid - d] : 0;
        __syncthreads();
        sm[tid] += t;
        __syncthreads();
    }
    if (i < n) rowptr[i] = sm[tid] - v;            // local exclusive prefix
    if (tid == 255) blocksum[blockIdx.x] = sm[255];
}

// Phase 2+3 fused: each block reduces blocksum[0..blockIdx) itself (nb<=256),
// adds the offset, inits the fill cursor and rowptr[n].
__global__ __launch_bounds__(256) void add_off2(
    int* __restrict__ rowptr, int* __restrict__ cur,
    const int* __restrict__ blocksum, int n, int E, int nb)
{
    __shared__ int sm[256];
    int tid = threadIdx.x;
    sm[tid] = (tid < nb && tid < (int)blockIdx.x) ? blocksum[tid] : 0;
    __syncthreads();
    #pragma unroll
    for (int d = 128; d > 0; d >>= 1) {
        if (tid < d) sm[tid] += sm[tid + d];
        __syncthreads();
    }
    int offv = sm[0];   // exclusive prefix of block sums
    int i = blockIdx.x * 256 + tid;
    if (i < n) {
        int r = rowptr[i] + offv;
        rowptr[i] = r;
        cur[i] = r;
    }
    if (blockIdx.x == 0 && tid == 0) rowptr[n] = E;
}

// ---------------- MFMA GEMM body — LDS-FREE --------------------------------------
// out[i][j] = half( dinv[i] * sum_k X[i][k] W[k][j] ). B-fragments are read
// directly from global WT (32KB = exactly one CU's L1, hot after first block
// per CU). No __shared__ -> when fused with the fill, fill blocks keep full
// occupancy (R8's 34KB wlds capped everything at 4 blocks/CU).
// mfma_f32_16x16x32_f16: A[m=lane&15][k=quad*8+j]; B[k=quad*8+j][n=lane&15];
// D: row=quad*4+reg, col=lane&15.

template<bool F32IN>
__device__ __forceinline__ void gemm_body(
    const void* __restrict__ Xv, const __half* __restrict__ WT,
    const float* __restrict__ dinv, __half* __restrict__ out, int M, int bid)
{
    const int tid  = threadIdx.x;
    const int wave = tid >> 6, lane = tid & 63;
    const int quad = lane >> 4, l15 = lane & 15;
    const int rowA = bid * 64 + wave * 16 + l15;
    const int rowc = (rowA < M) ? rowA : (M - 1);   // clamp (dup row, never stored)

    half8 afr[4];
    if (F32IN) {
        const float* X = (const float*)Xv;
        #pragma unroll
        for (int kc = 0; kc < 4; kc++) {
            const floatx4* p = (const floatx4*)(X + (size_t)rowc * NF + kc * 32 + quad * 8);
            floatx4 u = p[0], v = p[1];
            half8 a;
            a[0] = (_Float16)u[0]; a[1] = (_Float16)u[1];
            a[2] = (_Float16)u[2]; a[3] = (_Float16)u[3];
            a[4] = (_Float16)v[0]; a[5] = (_Float16)v[1];
            a[6] = (_Float16)v[2]; a[7] = (_Float16)v[3];
            afr[kc] = a;
        }
    } else {
        const __half* X = (const __half*)Xv;
        #pragma unroll
        for (int kc = 0; kc < 4; kc++)
            afr[kc] = *(const half8*)(X + (size_t)rowc * NF + kc * 32 + quad * 8);
    }

    floatx4 acc[8];
    #pragma unroll
    for (int ct = 0; ct < 8; ct++) { floatx4 z = {0.f, 0.f, 0.f, 0.f}; acc[ct] = z; }

    #pragma unroll
    for (int kc = 0; kc < 4; kc++) {
        #pragma unroll
        for (int ct = 0; ct < 8; ct++) {
            half8 b = *(const half8*)(WT + (size_t)(ct * 16 + l15) * NF + kc * 32 + quad * 8);
            acc[ct] = __builtin_amdgcn_mfma_f32_16x16x32_f16(afr[kc], b, acc[ct], 0, 0, 0);
        }
    }

    const int orow0 = bid * 64 + wave * 16 + quad * 4;
    #pragma unroll
    for (int r = 0; r < 4; r++) {
        int orow = orow0 + r;
        if (orow < M) {
            float s = dinv[orow];
            #pragma unroll
            for (int ct = 0; ct < 8; ct++)
                out[(size_t)orow * NF + ct * 16 + l15] = __float2half(acc[ct][r] * s);
        }
    }
}

// Fused: blocks [0, gemmBlocks) run layer-1 GEMM; the rest run the
// XCD-partitioned CSR fill, 4 edges/thread (int4). Both halves are 0-LDS so
// fill keeps ~8 blocks/CU. part<->XCD remains a fixed bijection.
__global__ __launch_bounds__(256) void fill_gemm1_k(
    const int* __restrict__ src, const int* __restrict__ dst,
    int* __restrict__ cur, int* __restrict__ csr, int E, int N,
    const float* __restrict__ X, const __half* __restrict__ WT,
    const float* __restrict__ dinv, __half* __restrict__ H, int gemmBlocks)
{
    int bid = blockIdx.x;
    if (bid < gemmBlocks) {
        gemm_body<true>(X, WT, dinv, H, N, bid);
    } else {
        int b = bid - gemmBlocks;
        int part = b & 7, chunk = b >> 3;
        int e = (chunk * 256 + threadIdx.x) * 4;
        int lo = (int)(((long long)part * N) >> 3);
        int hi = (int)(((long long)(part + 1) * N) >> 3);
        if (e + 3 < E) {
            int4 d = *(const int4*)(dst + e);
            int4 s = *(const int4*)(src + e);
            if (d.x >= lo && d.x < hi) csr[atomicAdd(&cur[d.x], 1)] = s.x;
            if (d.y >= lo && d.y < hi) csr[atomicAdd(&cur[d.y], 1)] = s.y;
            if (d.z >= lo && d.z < hi) csr[atomicAdd(&cur[d.z], 1)] = s.z;
            if (d.w >= lo && d.w < hi) csr[atomicAdd(&cur[d.w], 1)] = s.w;
        } else {
            for (int k = e; k < E; k++) {
                int d = dst[k];
                if (d >= lo && d < hi) csr[atomicAdd(&cur[d], 1)] = src[k];
            }
        }
    }
}

__global__ __launch_bounds__(256) void gemm2_k(
    const __half* __restrict__ A, const __half* __restrict__ WT,
    const float* __restrict__ dinv, __half* __restrict__ H, int M)
{
    gemm_body<false>(A, WT, dinv, H, M, blockIdx.x);
}

// ---------------- Aggregation: one wave per node, fp16 gather, fp32 accumulate --
// acc = hs[node] + sum_in hs[src]; res = dinv[node]*acc + bias.
// outh: half(relu(res)) (layer 1); else float res. 16 gathers in flight.

__global__ __launch_bounds__(256) void agg_k(
    const __half2* __restrict__ hs, const int* __restrict__ rowptr,
    const int* __restrict__ csr, const float* __restrict__ dinv,
    const float* __restrict__ bias, __half2* __restrict__ outh,
    float* __restrict__ outf, int n)
{
    int wave = threadIdx.x >> 6;
    int lane = threadIdx.x & 63;
    int node = blockIdx.x * 4 + wave;
    if (node >= n) return;

    const int HS = NF / 2;   // 64 half2 per row
    float2 acc = __half22float2(hs[(size_t)node * HS + lane]);  // self-loop

    int base = rowptr[node];
    int cnt  = rowptr[node + 1] - base;

    for (int off = 0; off < cnt; off += 64) {
        int m = min(64, cnt - off);
        int idx = 0;
        if (lane < m) idx = __builtin_nontemporal_load(&csr[base + off + lane]);
        int j = 0;
        for (; j + 15 < m; j += 16) {   // 16 gathers in flight
            int s[16];
            __half2 v[16];
            #pragma unroll
            for (int t = 0; t < 16; t++) s[t] = __shfl(idx, j + t, 64);
            #pragma unroll
            for (int t = 0; t < 16; t++) v[t] = hs[(size_t)s[t] * HS + lane];
            #pragma unroll
            for (int t = 0; t < 16; t++) {
                float2 f = __half22float2(v[t]);
                acc.x += f.x; acc.y += f.y;
            }
        }
        for (; j + 3 < m; j += 4) {     // 4-deep remainder
            int s0 = __shfl(idx, j, 64);
            int s1 = __shfl(idx, j + 1, 64);
            int s2 = __shfl(idx, j + 2, 64);
            int s3 = __shfl(idx, j + 3, 64);
            __half2 v0 = hs[(size_t)s0 * HS + lane];
            __half2 v1 = hs[(size_t)s1 * HS + lane];
            __half2 v2 = hs[(size_t)s2 * HS + lane];
            __half2 v3 = hs[(size_t)s3 * HS + lane];
            float2 f0 = __half22float2(v0), f1 = __half22float2(v1);
            float2 f2 = __half22float2(v2), f3 = __half22float2(v3);
            acc.x += (f0.x + f1.x) + (f2.x + f3.x);
            acc.y += (f0.y + f1.y) + (f2.y + f3.y);
        }
        for (; j < m; j++) {
            int s0 = __shfl(idx, j, 64);
            float2 f0 = __half22float2(hs[(size_t)s0 * HS + lane]);
            acc.x += f0.x; acc.y += f0.y;
        }
    }

    float s = dinv[node];
    float ox = s * acc.x + bias[2 * lane];
    float oy = s * acc.y + bias[2 * lane + 1];
    if (outh) {
        ox = fmaxf(ox, 0.f); oy = fmaxf(oy, 0.f);
        outh[(size_t)node * HS + lane] = __floats2half2_rn(ox, oy);
    } else {
        ((float2*)(outf + (size_t)node * NF))[lane] = make_float2(ox, oy);
    }
}

// ---------------- launch ----------------

extern "C" void kernel_launch(void* const* d_in, const int* in_sizes, int n_in,
                              void* d_out, int out_size, void* d_ws, size_t ws_size,
                              hipStream_t stream) {
    const float* x  = (const float*)d_in[0];
    const int*   ei = (const int*)d_in[1];
    const float* W1 = (const float*)d_in[2];
    const float* b1 = (const float*)d_in[3];
    const float* W2 = (const float*)d_in[4];
    const float* b2 = (const float*)d_in[5];
    float* out = (float*)d_out;

    const int N = in_sizes[0] / NF;   // 50000
    const int E = in_sizes[1] / 2;    // 800000
    const int* src = ei;
    const int* dst = ei + E;

    char* ws = (char*)d_ws;
    size_t off = 0;
    auto alloc = [&](size_t bytes) {
        void* p = ws + off;
        off += bytes;
        off = (off + 63) & ~(size_t)63;
        return p;
    };
    int*    cnt    = (int*)alloc((size_t)N * 4);        // reused as fill cursor
    int*    rowptr = (int*)alloc((size_t)(N + 1) * 4);
    int*    csr    = (int*)alloc((size_t)E * 4);
    float*  dinv   = (float*)alloc((size_t)N * 4);
    int*    bsum   = (int*)alloc((size_t)256 * 4);
    __half* WT1    = (__half*)alloc((size_t)NF * NF * 2);
    __half* WT2    = (__half*)alloc((size_t)NF * NF * 2);
    __half* H16    = (__half*)alloc((size_t)N * NF * 2);
    __half* A16    = (__half*)alloc((size_t)N * NF * 2);

    int nb = (N + 255) / 256;     // 196 blocks (<= 256, required by add_off2)
    int cb = (E / 4 + 255) / 256;
    int fb = ((E / 4 + 255) / 256) * 8;   // fill: 4 edges/thread, 8 parts
    int gb = (N + 63) / 64;
    int ab = (N + 3) / 4;

    prep_k<<<nb + 128, 256, 0, stream>>>(cnt, N, nb, W1, W2, WT1, WT2);
    count_k<<<cb, 256, 0, stream>>>(dst, cnt, E);
    pscan_local<<<nb, 256, 0, stream>>>(cnt, dinv, rowptr, bsum, N);
    add_off2<<<nb, 256, 0, stream>>>(rowptr, cnt, bsum, N, E, nb);
    fill_gemm1_k<<<gb + fb, 256, 0, stream>>>(src, dst, cnt, csr, E, N,
                                              x, WT1, dinv, H16, gb);
    agg_k<<<ab, 256, 0, stream>>>((const __half2*)H16, rowptr, csr, dinv, b1,
                                  (__half2*)A16, nullptr, N);
    gemm2_k<<<gb, 256, 0, stream>>>(A16, WT2, dinv, H16, N);
    agg_k<<<ab, 256, 0, stream>>>((const __half2*)H16, rowptr, csr, dinv, b2,
                                  nullptr, out, N);
}